// Round 1
// baseline (14.507 us; speedup 1.0000x reference)
//
#include <hip/hip_runtime.h>

#define NB 4          // batch
#define N_IN 1024
#define N_OUT 1024
#define IN_CH_RAW 7
#define CH 8          // density + 7
#define OUT_CH 16

__global__ __launch_bounds__(256) void convdeepset_kernel(
    const float* __restrict__ cx,     // (B, N_IN, 1)
    const float* __restrict__ cy,     // (B, N_IN, 7)
    const float* __restrict__ t,      // (B, N_OUT, 1)
    const float* __restrict__ sigma,  // (8,)
    const float* __restrict__ W,      // (8, 16)
    const float* __restrict__ bias,   // (16,)
    float* __restrict__ out)          // (B, N_OUT, 16)
{
    __shared__ float xs[N_IN];
    __shared__ float ys[N_IN * IN_CH_RAW];   // flat [i*7 + c]

    const int tid = threadIdx.x;
    const int bi  = blockIdx.x;          // 1024 blocks, 4 output points each
    const int b   = bi >> 8;             // 256 blocks per batch

    // ---- stage per-batch context into LDS (coalesced float4) ----
    const float4* cy4 = reinterpret_cast<const float4*>(cy + (size_t)b * N_IN * IN_CH_RAW);
    float4* ys4 = reinterpret_cast<float4*>(ys);
    #pragma unroll
    for (int idx = tid; idx < N_IN * IN_CH_RAW / 4; idx += 256) ys4[idx] = cy4[idx];
    for (int idx = tid; idx < N_IN; idx += 256) xs[idx] = cx[b * N_IN + idx];
    __syncthreads();

    const int wave = tid >> 6;
    const int lane = tid & 63;
    const int p    = bi * 4 + wave;      // global output-point index
    const int o    = p & (N_OUT - 1);
    const float t_o = t[b * N_OUT + o];

    // kc[c] = -0.5 / scales[c]^2 = -0.5 * exp(-2*sigma[c])
    float kc[CH];
    #pragma unroll
    for (int c = 0; c < CH; ++c) kc[c] = -0.5f * __expf(-2.0f * sigma[c]);

    float acc[CH];
    #pragma unroll
    for (int c = 0; c < CH; ++c) acc[c] = 0.0f;

    // ---- main reduction: lanes split i, 16 iters each ----
    for (int ii = lane; ii < N_IN; ii += 64) {
        const float dx = xs[ii] - t_o;
        const float d2 = dx * dx;
        acc[0] += __expf(d2 * kc[0]);                  // density channel (y==1)
        #pragma unroll
        for (int c = 1; c < CH; ++c)
            acc[c] += __expf(d2 * kc[c]) * ys[ii * IN_CH_RAW + (c - 1)];
    }

    // ---- wave butterfly reduce (64 lanes) ----
    #pragma unroll
    for (int m = 1; m < 64; m <<= 1) {
        #pragma unroll
        for (int c = 0; c < CH; ++c)
            acc[c] += __shfl_xor(acc[c], m, 64);
    }

    // ---- normalize + linear head ----
    const float inv = 1.0f / (acc[0] + 1e-8f);
    float agg[CH];
    agg[0] = acc[0];
    #pragma unroll
    for (int c = 1; c < CH; ++c) agg[c] = acc[c] * inv;

    if (lane < OUT_CH) {
        float v = bias[lane];
        #pragma unroll
        for (int c = 0; c < CH; ++c) v += agg[c] * W[c * OUT_CH + lane];
        out[(size_t)p * OUT_CH + lane] = v;
    }
}

extern "C" void kernel_launch(void* const* d_in, const int* in_sizes, int n_in,
                              void* d_out, int out_size, void* d_ws, size_t ws_size,
                              hipStream_t stream) {
    const float* cx    = (const float*)d_in[0];
    const float* cy    = (const float*)d_in[1];
    const float* t     = (const float*)d_in[2];
    const float* sigma = (const float*)d_in[3];
    const float* W     = (const float*)d_in[4];
    const float* bias  = (const float*)d_in[5];
    float* out = (float*)d_out;

    const int points = NB * N_OUT;           // 4096
    dim3 grid(points / 4), block(256);
    convdeepset_kernel<<<grid, block, 0, stream>>>(cx, cy, t, sigma, W, bias, out);
}

// Round 2
// 10.809 us; speedup vs baseline: 1.3421x; 1.3421x over previous
//
#include <hip/hip_runtime.h>

#define NB 4
#define N_IN 1024
#define N_OUT 1024
#define IN_CH_RAW 7
#define CH 8
#define OUT_CH 16
#define LOG2E 1.4426950408889634f

// 512 blocks x 256 threads. Block bi: batch b = bi>>7, handles 8 output
// points (4 waves x 2 points). LDS: packed rows {x, y0..y6} as 2 float4,
// XOR-swizzled so stride-32B ds_read_b128 hits all 8 16B slots per 8 rows.
__global__ __launch_bounds__(256) void convdeepset_kernel(
    const float* __restrict__ cx,     // (B, N_IN, 1)
    const float* __restrict__ cy,     // (B, N_IN, 7)
    const float* __restrict__ t,      // (B, N_OUT, 1)
    const float* __restrict__ sigma,  // (8,)
    const float* __restrict__ W,      // (8, 16)
    const float* __restrict__ bias,   // (16,)
    float* __restrict__ out)          // (B, N_OUT, 16)
{
    __shared__ float4 lds4[N_IN * 2];   // 32 KB

    const int tid = threadIdx.x;
    const int bi  = blockIdx.x;
    const int b   = bi >> 7;            // 128 blocks per batch

    // ---- stage packed context rows into LDS (swizzled) ----
    #pragma unroll
    for (int k = 0; k < 4; ++k) {
        const int r = tid + 256 * k;
        const float x = cx[b * N_IN + r];
        const float* yr = cy + ((size_t)(b * N_IN + r)) * IN_CH_RAW;
        const float4 q0 = make_float4(x,     yr[0], yr[1], yr[2]);
        const float4 q1 = make_float4(yr[3], yr[4], yr[5], yr[6]);
        const int idx = (r * 2) ^ ((r & 4) >> 2);
        lds4[idx]     = q0;
        lds4[idx ^ 1] = q1;
    }

    // ---- per-thread constants from sigma ----
    const float s0 = sigma[0];
    bool uni = true;
    float kc2[CH];
    #pragma unroll
    for (int c = 0; c < CH; ++c) {
        const float sc = sigma[c];
        kc2[c] = -0.5f * LOG2E * __expf(-2.0f * sc);
        uni = uni && (sc == s0);
    }
    const float ks = __expf(-s0) * sqrtf(0.5f * LOG2E);

    __syncthreads();

    const int wave = tid >> 6;
    const int lane = tid & 63;
    const int p0   = bi * 8 + wave * 2;     // even global point index
    const int o0   = p0 & (N_OUT - 1);
    const float t0 = t[b * N_OUT + o0];
    const float t1 = t[b * N_OUT + o0 + 1];
    const float tk0 = t0 * ks;
    const float tk1 = t1 * ks;

    float a0[CH], a1[CH];
    #pragma unroll
    for (int c = 0; c < CH; ++c) { a0[c] = 0.0f; a1[c] = 0.0f; }

    if (uni) {
        // fast path: one exp weight shared by all 8 channels
        #pragma unroll 4
        for (int k = 0; k < 16; ++k) {
            const int ii  = lane + 64 * k;
            const int idx = (ii * 2) ^ ((ii & 4) >> 2);
            const float4 q0 = lds4[idx];
            const float4 q1 = lds4[idx ^ 1];
            const float xk = q0.x * ks;
            const float d0 = xk - tk0;
            const float d1 = xk - tk1;
            const float w0 = exp2f(-(d0 * d0));
            const float w1 = exp2f(-(d1 * d1));
            a0[0] += w0;        a1[0] += w1;
            a0[1] += w0 * q0.y; a1[1] += w1 * q0.y;
            a0[2] += w0 * q0.z; a1[2] += w1 * q0.z;
            a0[3] += w0 * q0.w; a1[3] += w1 * q0.w;
            a0[4] += w0 * q1.x; a1[4] += w1 * q1.x;
            a0[5] += w0 * q1.y; a1[5] += w1 * q1.y;
            a0[6] += w0 * q1.z; a1[6] += w1 * q1.z;
            a0[7] += w0 * q1.w; a1[7] += w1 * q1.w;
        }
    } else {
        // general path: per-channel scales
        #pragma unroll 2
        for (int k = 0; k < 16; ++k) {
            const int ii  = lane + 64 * k;
            const int idx = (ii * 2) ^ ((ii & 4) >> 2);
            const float4 q0 = lds4[idx];
            const float4 q1 = lds4[idx ^ 1];
            const float y[IN_CH_RAW] = {q0.y, q0.z, q0.w, q1.x, q1.y, q1.z, q1.w};
            const float dx0 = q0.x - t0, d20 = dx0 * dx0;
            const float dx1 = q0.x - t1, d21 = dx1 * dx1;
            a0[0] += exp2f(d20 * kc2[0]);
            a1[0] += exp2f(d21 * kc2[0]);
            #pragma unroll
            for (int c = 1; c < CH; ++c) {
                a0[c] += exp2f(d20 * kc2[c]) * y[c - 1];
                a1[c] += exp2f(d21 * kc2[c]) * y[c - 1];
            }
        }
    }

    // ---- wave butterfly reduce ----
    #pragma unroll
    for (int m = 1; m < 64; m <<= 1) {
        #pragma unroll
        for (int c = 0; c < CH; ++c) {
            a0[c] += __shfl_xor(a0[c], m, 64);
            a1[c] += __shfl_xor(a1[c], m, 64);
        }
    }

    // ---- normalize + linear head: lanes 0-15 -> p0, lanes 16-31 -> p0+1 ----
    if (lane < 32) {
        const int sel = lane >> 4;
        const int col = lane & 15;
        float a[CH];
        #pragma unroll
        for (int c = 0; c < CH; ++c) a[c] = sel ? a1[c] : a0[c];
        const float inv = 1.0f / (a[0] + 1e-8f);
        float v = bias[col] + a[0] * W[col];
        #pragma unroll
        for (int c = 1; c < CH; ++c) v += (a[c] * inv) * W[c * OUT_CH + col];
        out[(size_t)(p0 + sel) * OUT_CH + col] = v;
    }
}

extern "C" void kernel_launch(void* const* d_in, const int* in_sizes, int n_in,
                              void* d_out, int out_size, void* d_ws, size_t ws_size,
                              hipStream_t stream) {
    const float* cx    = (const float*)d_in[0];
    const float* cy    = (const float*)d_in[1];
    const float* t     = (const float*)d_in[2];
    const float* sigma = (const float*)d_in[3];
    const float* W     = (const float*)d_in[4];
    const float* bias  = (const float*)d_in[5];
    float* out = (float*)d_out;

    dim3 grid(NB * N_OUT / 8), block(256);
    convdeepset_kernel<<<grid, block, 0, stream>>>(cx, cy, t, sigma, W, bias, out);
}

// Round 3
// 9.983 us; speedup vs baseline: 1.4532x; 1.0828x over previous
//
#include <hip/hip_runtime.h>

#define NB 4
#define N_IN 1024
#define N_OUT 1024
#define IN_CH_RAW 7
#define CH 8
#define OUT_CH 16
#define LOG2E 1.4426950408889634f

// Full-wave sum via DPP (no LDS traffic): row_shr 1/2/4/8 + row_bcast 15/31,
// total lands in lane 63; readlane broadcasts it wave-uniform.
__device__ __forceinline__ float wave_sum(float x) {
    float s = x;
    int v;
    v = __builtin_amdgcn_update_dpp(0, __float_as_int(s), 0x111, 0xF, 0xF, true); s += __int_as_float(v);
    v = __builtin_amdgcn_update_dpp(0, __float_as_int(s), 0x112, 0xF, 0xF, true); s += __int_as_float(v);
    v = __builtin_amdgcn_update_dpp(0, __float_as_int(s), 0x114, 0xF, 0xF, true); s += __int_as_float(v);
    v = __builtin_amdgcn_update_dpp(0, __float_as_int(s), 0x118, 0xF, 0xF, true); s += __int_as_float(v);
    v = __builtin_amdgcn_update_dpp(0, __float_as_int(s), 0x142, 0xF, 0xF, true); s += __int_as_float(v);
    v = __builtin_amdgcn_update_dpp(0, __float_as_int(s), 0x143, 0xF, 0xF, true); s += __int_as_float(v);
    return __int_as_float(__builtin_amdgcn_readlane(__float_as_int(s), 63));
}

// 512 blocks x 256 threads; block bi handles 8 output points (4 waves x 2).
// LDS rows {x,y0..y6} packed as 2 float4, slot-XOR swizzled (row bit2 -> granule
// bit0) so the stride-32B ds_read_b128 spreads over all 8 bank-groups.
__global__ __launch_bounds__(256) void convdeepset_kernel(
    const float* __restrict__ cx,     // (B, N_IN, 1)
    const float* __restrict__ cy,     // (B, N_IN, 7)
    const float* __restrict__ t,      // (B, N_OUT, 1)
    const float* __restrict__ sigma,  // (8,)
    const float* __restrict__ W,      // (8, 16)
    const float* __restrict__ bias,   // (16,)
    float* __restrict__ out)          // (B, N_OUT, 16)
{
    __shared__ float4 lds4[N_IN * 2];   // 32 KB

    const int tid = threadIdx.x;
    const int bi  = blockIdx.x;
    const int b   = bi >> 7;            // 128 blocks per batch

    // ---- stage packed context rows into LDS (swizzled) ----
    #pragma unroll
    for (int k = 0; k < 4; ++k) {
        const int r = tid + 256 * k;
        const float x = cx[b * N_IN + r];
        const float* yr = cy + ((size_t)(b * N_IN + r)) * IN_CH_RAW;
        const float4 q0 = make_float4(x,     yr[0], yr[1], yr[2]);
        const float4 q1 = make_float4(yr[3], yr[4], yr[5], yr[6]);
        const int idx = (r * 2) ^ ((r & 4) >> 2);
        lds4[idx]     = q0;
        lds4[idx ^ 1] = q1;
    }

    // ---- per-thread constants from sigma (overlaps staging latency) ----
    const float s0 = sigma[0];
    bool uni = true;
    float kc2[CH];
    #pragma unroll
    for (int c = 0; c < CH; ++c) {
        const float sc = sigma[c];
        kc2[c] = -0.5f * LOG2E * __expf(-2.0f * sc);
        uni = uni && (sc == s0);
    }
    const float ks = __expf(-s0) * sqrtf(0.5f * LOG2E);

    const int wave = tid >> 6;
    const int lane = tid & 63;
    const int p0   = bi * 8 + wave * 2;
    const int o0   = p0 & (N_OUT - 1);
    const float t0 = t[b * N_OUT + o0];
    const float t1 = t[b * N_OUT + o0 + 1];
    const float ntk0 = -(t0 * ks);
    const float ntk1 = -(t1 * ks);

    // fixed per-lane swizzled slots; k-iters differ by +128 slots (2048 B imm)
    const int slot0 = (lane * 2) ^ ((lane & 4) >> 2);
    const int slot1 = slot0 ^ 1;

    float a0[CH], a1[CH];
    #pragma unroll
    for (int c = 0; c < CH; ++c) { a0[c] = 0.0f; a1[c] = 0.0f; }

    __syncthreads();

    if (uni) {
        #pragma unroll
        for (int k = 0; k < 16; ++k) {
            const float4 q0 = lds4[slot0 + 128 * k];
            const float4 q1 = lds4[slot1 + 128 * k];
            const float d0 = __fmaf_rn(q0.x, ks, ntk0);
            const float d1 = __fmaf_rn(q0.x, ks, ntk1);
            const float w0 = exp2f(-(d0 * d0));
            const float w1 = exp2f(-(d1 * d1));
            a0[0] += w0;        a1[0] += w1;
            a0[1] += w0 * q0.y; a1[1] += w1 * q0.y;
            a0[2] += w0 * q0.z; a1[2] += w1 * q0.z;
            a0[3] += w0 * q0.w; a1[3] += w1 * q0.w;
            a0[4] += w0 * q1.x; a1[4] += w1 * q1.x;
            a0[5] += w0 * q1.y; a1[5] += w1 * q1.y;
            a0[6] += w0 * q1.z; a1[6] += w1 * q1.z;
            a0[7] += w0 * q1.w; a1[7] += w1 * q1.w;
        }
    } else {
        #pragma unroll 2
        for (int k = 0; k < 16; ++k) {
            const float4 q0 = lds4[slot0 + 128 * k];
            const float4 q1 = lds4[slot1 + 128 * k];
            const float y[IN_CH_RAW] = {q0.y, q0.z, q0.w, q1.x, q1.y, q1.z, q1.w};
            const float dx0 = q0.x - t0, d20 = dx0 * dx0;
            const float dx1 = q0.x - t1, d21 = dx1 * dx1;
            a0[0] += exp2f(d20 * kc2[0]);
            a1[0] += exp2f(d21 * kc2[0]);
            #pragma unroll
            for (int c = 1; c < CH; ++c) {
                a0[c] += exp2f(d20 * kc2[c]) * y[c - 1];
                a1[c] += exp2f(d21 * kc2[c]) * y[c - 1];
            }
        }
    }

    // ---- DPP wave reduction: results wave-uniform ----
    float r0[CH], r1[CH];
    #pragma unroll
    for (int c = 0; c < CH; ++c) { r0[c] = wave_sum(a0[c]); r1[c] = wave_sum(a1[c]); }

    // ---- normalize + linear head: lanes 0-15 -> p0, 16-31 -> p0+1 ----
    if (lane < 32) {
        const int sel = lane >> 4;
        const int col = lane & 15;
        float a[CH];
        #pragma unroll
        for (int c = 0; c < CH; ++c) a[c] = sel ? r1[c] : r0[c];
        const float inv = 1.0f / (a[0] + 1e-8f);
        float v = bias[col] + a[0] * W[col];
        #pragma unroll
        for (int c = 1; c < CH; ++c) v += (a[c] * inv) * W[c * OUT_CH + col];
        out[(size_t)(p0 + sel) * OUT_CH + col] = v;
    }
}

extern "C" void kernel_launch(void* const* d_in, const int* in_sizes, int n_in,
                              void* d_out, int out_size, void* d_ws, size_t ws_size,
                              hipStream_t stream) {
    const float* cx    = (const float*)d_in[0];
    const float* cy    = (const float*)d_in[1];
    const float* t     = (const float*)d_in[2];
    const float* sigma = (const float*)d_in[3];
    const float* W     = (const float*)d_in[4];
    const float* bias  = (const float*)d_in[5];
    float* out = (float*)d_out;

    dim3 grid(NB * N_OUT / 8), block(256);
    convdeepset_kernel<<<grid, block, 0, stream>>>(cx, cy, t, sigma, W, bias, out);
}